// Round 10
// baseline (1605.518 us; speedup 1.0000x reference)
//
#include <hip/hip_runtime.h>
#include <hip/hip_bf16.h>

// ---------------- sizes ----------------
#define T_STEPS 256
#define MDIM 1024
#define MROWS 512
#define NBLK 128
#define GRID NBLK
#define NTHR 512

// ws float offsets
#define OFF_WGB     0u                      // bf16 [1024][4096] interleaved gates (2M floats)
#define OFF_WATT    2097152u                // fp32 [1024][1024] W_attnh top, transposed
#define OFF_HPRET   3145728u                // fp32 [1024][512]  Hpre TRANSPOSED
#define OFF_XIOU    3670016u                // fp32 [256][3072]
#define OFF_XF      4456448u                // fp32 [256][1024]
#define OFF_G       4718592u                // bf16 [512][4096]  G = H @ Wg
#define OFF_HT      5767168u                // fp32 [1024][512]  H transposed
#define OFF_HCOL    6291456u                // fp32 [1024]
#define OFF_SCORED  6297600u                // f64 [2][16][512] count-biased score copies, COPY-MAJOR (zeroed)
#define OFF_HLINE   6330368u                // u64 [128][8]: 8 packets {f32 h, u32 epoch} per block (zeroed)

// R22 score reduction: 16 copies (2 per XCD), RMW depth 8 (was 16).
// cidx = x*2 + (y&1): 8 blocks per copy, all on XCD x (single-XCD atomic
// lines, R16 erratum). Settled copy = 8*BIAS32 + partial; de-bias
// SUBBIAS=2^35 per copy (Sterbenz-exact). Poll width 16 at 65K pollers
// (gentle regime; R19's storm was 131K x 32-wide).
#define BIAS32  4294967296.0                // 2^32
#define SUBBIAS (8.0 * 4294967296.0)        // 2^35
#define DONE_TH (8.0 * 4294967296.0 - 1073741824.0)   // 8*2^32 - 2^30

typedef __attribute__((ext_vector_type(8))) short short8;
typedef __attribute__((ext_vector_type(4))) float f32x4;

__device__ inline float fast_tanh(float v) {
    float x = fminf(fmaxf(v, -15.f), 15.f);
    float z = __expf(2.f * x);
    return (z - 1.f) / (z + 1.f);
}
__device__ inline float sigm(float v) { return 1.f / (1.f + __expf(-v)); }

__device__ inline float wave_red(float v) {
#pragma unroll
    for (int s = 32; s > 0; s >>= 1) v += __shfl_down(v, s, 64);
    return v;
}

__device__ __host__ inline unsigned short f2b(float f) {
    __hip_bfloat16 h = __float2bfloat16(f);
    return *(unsigned short*)&h;
}
__device__ inline float b2f(unsigned short u) {
    union { unsigned i; float f; } v; v.i = ((unsigned)u) << 16; return v.f;
}

// device-scope relaxed atomics
__device__ inline double gloadd(const double* p) {
    return __hip_atomic_load(p, __ATOMIC_RELAXED, __HIP_MEMORY_SCOPE_AGENT);
}
__device__ inline void gstored(double* p, double v) {
    __hip_atomic_store(p, v, __ATOMIC_RELAXED, __HIP_MEMORY_SCOPE_AGENT);
}
__device__ inline void gatomicd(double* p, double v) {
    __hip_atomic_fetch_add(p, v, __ATOMIC_RELAXED, __HIP_MEMORY_SCOPE_AGENT);
}
__device__ inline unsigned long long gloadu64(const unsigned long long* p) {
    return __hip_atomic_load(p, __ATOMIC_RELAXED, __HIP_MEMORY_SCOPE_AGENT);
}
__device__ inline void gstoreu64(unsigned long long* p, unsigned long long v) {
    __hip_atomic_store(p, v, __ATOMIC_RELAXED, __HIP_MEMORY_SCOPE_AGENT);
}

// -------- precompute kernels --------

__global__ void build_wg(const float* __restrict__ Wiouh, const float* __restrict__ Wfh,
                         unsigned short* __restrict__ Wgb) {
    int k = blockIdx.y;
    int g = blockIdx.x * 256 + threadIdx.x;
    unsigned a = f2b(Wiouh[k * 3072 + g]);
    unsigned b = f2b(Wiouh[k * 3072 + 1024 + g]);
    unsigned c = f2b(Wiouh[k * 3072 + 2048 + g]);
    unsigned d = f2b(Wfh[k * 1024 + g]);
    uint2 p; p.x = a | (b << 16); p.y = c | (d << 16);
    *(uint2*)(Wgb + (size_t)k * 4096 + 4 * g) = p;
}

__global__ void transpose_g(const float* __restrict__ src, float* __restrict__ dst,
                            int R, int C) {
    __shared__ float tile[32][33];
    int c = blockIdx.x * 32 + threadIdx.x;
    int r0 = blockIdx.y * 32;
    for (int i = threadIdx.y; i < 32; i += 8)
        tile[i][threadIdx.x] = src[(size_t)(r0 + i) * C + c];
    __syncthreads();
    int r = r0 + threadIdx.x;
    int c0 = blockIdx.x * 32;
    for (int i = threadIdx.y; i < 32; i += 8)
        dst[(size_t)(c0 + i) * R + r] = tile[threadIdx.x][i];
}

// R22: colsum from HT (contiguous per-k rows), 32 blocks (was 4).
__global__ void colsum2_k(const float* __restrict__ HT, float* __restrict__ out) {
    int k = blockIdx.x * 32 + (threadIdx.x >> 3);
    int sub = threadIdx.x & 7;
    const float* row = HT + (size_t)k * 512 + sub * 64;
    float s = 0.f;
#pragma unroll
    for (int j = 0; j < 16; j++) {
        float4 v = *(const float4*)(row + j * 4);
        s += v.x + v.y + v.z + v.w;
    }
#pragma unroll
    for (int d = 4; d > 0; d >>= 1) s += __shfl_down(s, d, 8);
    if (sub == 0) out[k] = s;
}

// bf16-MFMA 64x64 tile body (verified R21). fp32->bf16 staging, fp32 acc.
#define MFMA_TILE_BODY(Bptr, LDB, NC0)                                         \
    for (int kk = 0; kk < 1024; kk += 32) {                                    \
        const float4 a0 = *(const float4*)(A + (size_t)(m0 + ar) * 1024 + kk + ak);      \
        const float4 a1 = *(const float4*)(A + (size_t)(m0 + ar) * 1024 + kk + ak + 4);  \
        short8 av;                                                             \
        av[0] = f2b(a0.x); av[1] = f2b(a0.y); av[2] = f2b(a0.z); av[3] = f2b(a0.w); \
        av[4] = f2b(a1.x); av[5] = f2b(a1.y); av[6] = f2b(a1.z); av[7] = f2b(a1.w); \
        short8 bv;                                                             \
        _Pragma("unroll")                                                      \
        for (int i = 0; i < 8; i++)                                            \
            bv[i] = f2b((Bptr)[(size_t)(kk + bk + i) * (LDB) + (NC0) + bn]);   \
        __syncthreads();                                                       \
        *(short8*)(As + ar * 40 + ak) = av;                                    \
        *(short8*)(Bs + bn * 40 + bk) = bv;                                    \
        __syncthreads();                                                       \
        const short8 af = *(const short8*)(As + (w * 16 + fr) * 40 + fk);      \
        _Pragma("unroll")                                                      \
        for (int c = 0; c < 4; c++) {                                          \
            const short8 bf = *(const short8*)(Bs + (c * 16 + fr) * 40 + fk);  \
            acc[c] = __builtin_amdgcn_mfma_f32_16x16x32_bf16(af, bf, acc[c], 0, 0, 0); \
        }                                                                      \
    }

// Fused inputs-GEMM: [X_iou | X_f] = inputs @ [W_ioux | W_fx] + biases.
// grid (64, 4): cols 0..3071 -> X_iou, 3072..4095 -> X_f.
__global__ __launch_bounds__(256) void gemm_x(
    const float* __restrict__ A, const float* __restrict__ Wioux,
    const float* __restrict__ Wfx, const float* __restrict__ bioux,
    const float* __restrict__ biouh, const float* __restrict__ bfx,
    const float* __restrict__ bfh, float* __restrict__ Xiou,
    float* __restrict__ Xf) {
    __shared__ unsigned short As[64 * 40];
    __shared__ unsigned short Bs[64 * 40];
    const int t = threadIdx.x;
    const int n0g = blockIdx.x * 64, m0 = blockIdx.y * 64;
    const int l = t & 63, w = t >> 6;
    const int fr = l & 15, fk = (l >> 4) * 8;
    const int ar = t >> 2, ak = (t & 3) * 8;
    const int bn = t >> 2, bk = (t & 3) * 8;
    const float* B; const float* c1; const float* c2; float* C;
    int ldb, ldc, nc0;
    if (n0g < 3072) { B = Wioux; ldb = 3072; nc0 = n0g; C = Xiou; ldc = 3072; c1 = bioux; c2 = biouh; }
    else            { B = Wfx;   ldb = 1024; nc0 = n0g - 3072; C = Xf; ldc = 1024; c1 = bfx; c2 = bfh; }
    f32x4 acc[4] = {};
    MFMA_TILE_BODY(B, ldb, nc0)
#pragma unroll
    for (int c = 0; c < 4; c++)
#pragma unroll
        for (int r = 0; r < 4; r++) {
            int m = m0 + w * 16 + (l >> 4) * 4 + r;
            int n = nc0 + c * 16 + (l & 15);
            C[(size_t)m * ldc + n] = acc[c][r] + c1[n] + c2[n];
        }
}

// Fused hiddn-GEMM: cols 0..3071 -> Gb (W_iouh, interleave), 3072..4095 ->
// Gb (W_fh, slot 3), 4096..5119 -> HpreT (W_attnh bottom, +bias, transposed).
// grid (80, 8).
__global__ __launch_bounds__(256) void gemm_h(
    const float* __restrict__ A, const float* __restrict__ Wiouh,
    const float* __restrict__ Wfh, const float* __restrict__ Wat,
    const float* __restrict__ battnh, unsigned short* __restrict__ Gb,
    float* __restrict__ HpreT) {
    __shared__ unsigned short As[64 * 40];
    __shared__ unsigned short Bs[64 * 40];
    const int t = threadIdx.x;
    const int n0g = blockIdx.x * 64, m0 = blockIdx.y * 64;
    const int l = t & 63, w = t >> 6;
    const int fr = l & 15, fk = (l >> 4) * 8;
    const int ar = t >> 2, ak = (t & 3) * 8;
    const int bn = t >> 2, bk = (t & 3) * 8;
    const float* B; int ldb, nc0, mode;
    if (n0g < 3072)      { B = Wiouh; ldb = 3072; nc0 = n0g; mode = 0; }
    else if (n0g < 4096) { B = Wfh;   ldb = 1024; nc0 = n0g - 3072; mode = 1; }
    else                 { B = Wat;   ldb = 1024; nc0 = n0g - 4096; mode = 2; }
    f32x4 acc[4] = {};
    MFMA_TILE_BODY(B, ldb, nc0)
#pragma unroll
    for (int c = 0; c < 4; c++)
#pragma unroll
        for (int r = 0; r < 4; r++) {
            int m = m0 + w * 16 + (l >> 4) * 4 + r;
            int n = nc0 + c * 16 + (l & 15);
            float v = acc[c][r];
            if (mode == 0) {
                int cp = 4 * (n & 1023) + (n >> 10);
                Gb[(size_t)m * 4096 + cp] = f2b(v);
            } else if (mode == 1) {
                Gb[(size_t)m * 4096 + 4 * n + 3] = f2b(v);
            } else {
                HpreT[(size_t)n * 512 + m] = v + battnh[n];
            }
        }
}

__device__ inline float sum8(const float* s) {
    return s[0] + s[1] + s[2] + s[3] + s[4] + s[5] + s[6] + s[7];
}

// -------- persistent recurrent kernel --------
// R22 = R20 (verified 1295us) with two changes:
//  (1) score copies 8 -> 16 (2/XCD): RMW depth 16 -> 8; poll width 16.
//  (2) HcolW kernel folded into the prologue: hcw = sum_k Hcol[k]*wregf
//      (Hcol staged in hs, reduced via red[]) -- hcolw launch eliminated.
__global__ __launch_bounds__(NTHR, 2) void recurrent(
    const unsigned short* __restrict__ Wgb, const float* __restrict__ WatT,
    const float* __restrict__ HpreT, const float* __restrict__ HT,
    const float* __restrict__ Hcol, const unsigned short* __restrict__ Gb,
    const float* __restrict__ X_iou, const float* __restrict__ X_f,
    const float* __restrict__ Wa,
    unsigned long long* hline, double* scored, float* out) {

    const int b = blockIdx.x, t = threadIdx.x;
    const int x = b & 7, y = b >> 3;          // y in [0,16)
    const int g_col = x * 128 + y * 8;        // block's 8 output/attention cols
    const int j0 = x * 512 + y * 32;          // block's 32 interleaved gate cols
    const int cidx = x * 2 + (y & 1);         // score sub-copy (single-XCD lines)
    float creg = 0.f;                          // cell state (threads t<8)
    __shared__ float smem[2648];
    float* hs   = smem;          // 1056 padded h (current)
    float* le   = smem + 1056;   // 512 e
    float* red  = smem + 1568;   // [16][32] s1 partials (written in X overlap)
    float* red2 = smem + 2080;   // [16][32] s2 partials
    float* sred = smem + 2592;   // 8  (S partials, 1/wave)
    float* sred2= smem + 2600;   // 8  (P per col, 1/wave)
    float* dotb = smem + 2608;   // 32
    float* attr = smem + 2640;   // 8  (att_v per col, 1/wave)

    const int jt = t & 31, kq = t >> 5;       // gates: 16 k-groups x 32 cols
    const int li = t & 63, tr = t >> 6;       // lane, wave id (0..7)
    const int tl = t & 127, hi = t >> 7;      // h-poll: 4 thr/line, 2 packets

    // ---- hoist step-invariant loads into registers ----
    float wregf[64];
#pragma unroll
    for (int i = 0; i < 64; i++)
        wregf[i] = b2f(Wgb[(size_t)(kq * 64 + i) * 4096 + j0 + jt]);
    float gregf[32];
#pragma unroll
    for (int i = 0; i < 32; i++)
        gregf[i] = b2f(Gb[(size_t)(kq * 32 + i) * 4096 + j0 + jt]);
    float watreg[16];
#pragma unroll
    for (int i = 0; i < 16; i++)
        watreg[i] = WatT[(size_t)(g_col + tr) * 1024 + i * 64 + li];
    float htr[8], hpr[8], wa8[8];
#pragma unroll
    for (int i = 0; i < 8; i++)
        htr[i] = HT[(size_t)(g_col + tr) * 512 + li + 64 * i];
#pragma unroll
    for (int c = 0; c < 8; c++) {
        hpr[c] = HpreT[(size_t)(g_col + c) * 512 + t];
        wa8[c] = Wa[g_col + c];
    }
    const float hcolg = (t < 8) ? Hcol[g_col + t] : 0.f;

    // ---- prologue: hcw = sum_k Hcol[k] * Wgb[k][j0+jt] from wregf ----
    // (replaces the hcolw kernel; Hcol staged in hs, reduced via red)
    hs[t + (t >> 5)] = Hcol[t];
    { int k2 = t + 512; hs[k2 + (k2 >> 5)] = Hcol[t + 512]; }
    __syncthreads();
    {
        float hp = 0.f;
#pragma unroll
        for (int i = 0; i < 64; i++) {
            int k = kq * 64 + i;
            hp = fmaf(hs[k + (k >> 5)], wregf[i], hp);
        }
        red[kq * 32 + jt] = hp;
    }
    __syncthreads();
    float hcw = 0.f;
    if (t < 32) {
#pragma unroll
        for (int q = 0; q < 16; q++) hcw += red[q * 32 + t];
    }
    __syncthreads();
    // prime: s1 partials = 0 for step 0 (hs fully rewritten in X(0))
    red[kq * 32 + jt] = 0.f;

    for (int st = 0; st < T_STEPS; st++) {
        // ---- Y: e (poll 16 strided copies) + gates + h packets + out ----
        float xi0 = 0.f, xi1 = 0.f, xi2 = 0.f, xf0 = 0.f;
        if (t < 8) {                      // issued before poll: latency hidden
            int g = g_col + t;
            xi0 = X_iou[(size_t)st * 3072 + g];
            xi1 = X_iou[(size_t)st * 3072 + 1024 + g];
            xi2 = X_iou[(size_t)st * 3072 + 2048 + g];
            xf0 = X_f[(size_t)st * 1024 + g];
        }
        float sc = 0.f;
        if (st > 0) {
            const double* sp = scored + (size_t)((st + 1) & 1) * 8192 + t;
            double vv[16];
            for (;;) {
                bool ok = true;
#pragma unroll
                for (int c = 0; c < 16; c++) {
                    vv[c] = gloadd(sp + c * 512);
                    ok = ok && (vv[c] > DONE_TH);
                }
                if (ok) break;
                __builtin_amdgcn_s_sleep(1);
            }
            double accd = 0.0;
#pragma unroll
            for (int c = 0; c < 16; c++) accd += (vv[c] - SUBBIAS);
            sc = (float)accd;
        }
        float evv = __expf(sc);
        le[t] = evv;
        float sv = wave_red(evv);
        if ((t & 63) == 0) sred[t >> 6] = sv;
        __syncthreads();                       // #1
        // s2 (G-correction) from registers: rows kq*32+i
        float a2 = 0.f;
#pragma unroll
        for (int i = 0; i < 32; i++)
            a2 = fmaf(le[kq * 32 + i], gregf[i], a2);
        red2[kq * 32 + jt] = a2;
        // P for block's 8 out-cols: wave tr owns col g_col+tr
        float pp = 0.f;
#pragma unroll
        for (int i = 0; i < 8; i++)
            pp = fmaf(le[li + 64 * i], htr[i], pp);
        pp = wave_red(pp);
        if ((t & 63) == 0) sred2[t >> 6] = pp;
        __syncthreads();                       // #2
        if (t < 32) {                          // wave-0 writes dotb...
            float s1 = 0.f, s2 = 0.f;
#pragma unroll
            for (int q = 0; q < 16; q++) { s1 += red[q * 32 + t]; s2 += red2[q * 32 + t]; }
            float S = sum8(sred);
            float invS = (st == 0) ? 0.f : 1.f / S;
            float hw = (st == 0) ? 0.f : hcw;
            dotb[t] = s1 + hw - invS * s2;
        }
        if (t < 8) {                           // ...read also wave-0: in-order LDS
            int g = g_col + t;
            if (st > 0) {
                float S = sum8(sred);
                float P = sred2[t];
                out[(size_t)(st - 1) * 1024 + g] =
                    hcolg + hs[g + (g >> 5)] - P / S;
            }
            float di = dotb[t * 4 + 0] + xi0;
            float doo = dotb[t * 4 + 1] + xi1;
            float du = dotb[t * 4 + 2] + xi2;
            float df = dotb[t * 4 + 3] + xf0;
            float ig = sigm(di), og = sigm(doo), fg = sigm(df);
            float ug = fast_tanh(du);
            creg = ig * ug + fg * creg;
            float hv = og * fast_tanh(creg);
            // fused payload+flag: one 8B single-copy-atomic packet
            unsigned long long pkt =
                ((unsigned long long)(unsigned)(st + 1) << 32) | __float_as_uint(hv);
            gstoreu64(hline + (size_t)b * 8 + t, pkt);
        }
        __syncthreads();                       // #4: hs rewritten in X below

        // ---- X: poll-with-payload h -> LDS, att_v, biased f64 adds ----
        {
            const unsigned long long* lp = hline + (size_t)tl * 8 + hi * 2;
            const unsigned tgt = (unsigned)(st + 1);
            unsigned long long u0, u1;
            for (;;) {
                u0 = gloadu64(lp);
                u1 = gloadu64(lp + 1);
                if ((unsigned)(u0 >> 32) >= tgt && (unsigned)(u1 >> 32) >= tgt) break;
                __builtin_amdgcn_s_sleep(1);
            }
            int gc = (tl & 7) * 128 + (tl >> 3) * 8 + hi * 2;
            union { unsigned u; float f; } c0, c1;
            c0.u = (unsigned)u0; c1.u = (unsigned)u1;
            hs[gc + (gc >> 5)] = c0.f;
            int g1 = gc + 1; hs[g1 + (g1 >> 5)] = c1.f;
        }
        __syncthreads();                       // #5: hs ready AND all 128 lines
                                               // verified >= st+1 block-wide
        // zero the buffer all Y(st) consumed: safe after #5 (every block has
        // passed its Y(st) reads, proven by the 128 epochs). 64 doubles per
        // block cover the 8192-double buffer exactly once.
        if (t < 64)
            gstored(scored + (size_t)((st + 1) & 1) * 8192 + (size_t)b * 64 + t, 0.0);
        {
            // att_v: wave tr computes col g_col+tr (16 fma/lane from hs)
            float acc = 0.f;
#pragma unroll
            for (int i = 0; i < 16; i++) {
                int k = i * 64 + li;
                acc = fmaf(watreg[i], hs[k + (k >> 5)], acc);
            }
            acc = wave_red(acc);
            if ((t & 63) == 0) attr[t >> 6] = acc;
            __syncthreads();                   // #6 (implicit vmcnt(0): zeroes)
            float ps = 0.f;
#pragma unroll
            for (int c = 0; c < 8; c++)
                ps = fmaf(wa8[c], fast_tanh(hpr[c] + attr[c]), ps);
            __asm__ volatile("" ::: "memory");
            __builtin_amdgcn_s_waitcnt(0);     // own zero-store drained first
            gatomicd(scored + (size_t)(st & 1) * 8192 + (size_t)cidx * 512 + t,
                     (double)ps + BIAS32);
        }
        // s1 overlap for next step's gates (runs under the exchange latency)
        {
            float a = 0.f;
#pragma unroll
            for (int i = 0; i < 64; i++) {
                int k = kq * 64 + i;
                a = fmaf(hs[k + (k >> 5)], wregf[i], a);
            }
            red[kq * 32 + jt] = a;
        }
    }

    // ---- Epilogue: out[T-1] (Y(T) without gates) ----
    {
        const double* sp = scored + (size_t)((T_STEPS + 1) & 1) * 8192 + t;
        double vv[16];
        for (;;) {
            bool ok = true;
#pragma unroll
            for (int c = 0; c < 16; c++) {
                vv[c] = gloadd(sp + c * 512);
                ok = ok && (vv[c] > DONE_TH);
            }
            if (ok) break;
            __builtin_amdgcn_s_sleep(1);
        }
        double accd = 0.0;
#pragma unroll
        for (int c = 0; c < 16; c++) accd += (vv[c] - SUBBIAS);
        float evv = __expf((float)accd);
        le[t] = evv;
        float sv = wave_red(evv);
        if ((t & 63) == 0) sred[t >> 6] = sv;
        __syncthreads();
        float pp = 0.f;
#pragma unroll
        for (int i = 0; i < 8; i++)
            pp = fmaf(le[li + 64 * i], htr[i], pp);
        pp = wave_red(pp);
        if ((t & 63) == 0) sred2[t >> 6] = pp;
        __syncthreads();
        if (t < 8) {
            int g = g_col + t;
            float S = sum8(sred);
            float P = sred2[t];
            out[(size_t)(T_STEPS - 1) * 1024 + g] =
                hcolg + hs[g + (g >> 5)] - P / S;   // hs = h(T-1) from X(T-1)
        }
    }
}

extern "C" void kernel_launch(void* const* d_in, const int* in_sizes, int n_in,
                              void* d_out, int out_size, void* d_ws, size_t ws_size,
                              hipStream_t stream) {
    const float* inputs  = (const float*)d_in[0];
    const float* hiddn   = (const float*)d_in[1];
    const float* W_ioux  = (const float*)d_in[2];
    const float* b_ioux  = (const float*)d_in[3];
    const float* W_iouh  = (const float*)d_in[4];
    const float* b_iouh  = (const float*)d_in[5];
    const float* W_fx    = (const float*)d_in[6];
    const float* b_fx    = (const float*)d_in[7];
    const float* W_fh    = (const float*)d_in[8];
    const float* b_fh    = (const float*)d_in[9];
    const float* Wa      = (const float*)d_in[10];
    const float* W_attnh = (const float*)d_in[11];
    const float* b_attnh = (const float*)d_in[12];

    float* ws = (float*)d_ws;
    unsigned short* Wgb = (unsigned short*)(ws + OFF_WGB);
    float* WatT  = ws + OFF_WATT;
    float* HpreT = ws + OFF_HPRET;
    float* X_iou = ws + OFF_XIOU;
    float* X_f   = ws + OFF_XF;
    unsigned short* Gb = (unsigned short*)(ws + OFF_G);
    float* HT    = ws + OFF_HT;
    float* Hcol  = ws + OFF_HCOL;
    double* scored = (double*)(ws + OFF_SCORED);
    unsigned long long* hline = (unsigned long long*)(ws + OFF_HLINE);
    float* out   = (float*)d_out;

    // zero score copies (2x8192 f64 = 32768 floats) + hline (2048 floats)
    hipMemsetAsync(ws + OFF_SCORED, 0, (32768 + 2048) * sizeof(float), stream);

    build_wg<<<dim3(4, 1024), 256, 0, stream>>>(W_iouh, W_fh, Wgb);
    transpose_g<<<dim3(32, 32), dim3(32, 8), 0, stream>>>(W_attnh, WatT, 1024, 1024);
    transpose_g<<<dim3(32, 16), dim3(32, 8), 0, stream>>>(hiddn, HT, 512, 1024);
    colsum2_k<<<32, 256, 0, stream>>>(HT, Hcol);
    gemm_x<<<dim3(64, 4), 256, 0, stream>>>(inputs, W_ioux, W_fx, b_ioux, b_iouh,
                                            b_fx, b_fh, X_iou, X_f);
    gemm_h<<<dim3(80, 8), 256, 0, stream>>>(hiddn, W_iouh, W_fh,
                                            W_attnh + 1024 * 1024, b_attnh, Gb, HpreT);

    recurrent<<<GRID, NTHR, 0, stream>>>(Wgb, WatT, HpreT, HT, Hcol, Gb,
                                         X_iou, X_f, Wa, hline, scored, out);
}

// Round 11
// 1435.151 us; speedup vs baseline: 1.1187x; 1.1187x over previous
//
#include <hip/hip_runtime.h>
#include <hip/hip_bf16.h>

// ---------------- sizes ----------------
#define T_STEPS 256
#define MDIM 1024
#define MROWS 512
#define NBLK 128
#define GRID NBLK
#define NTHR 512

// ws float offsets
#define OFF_WGB     0u                      // bf16 [1024][4096] interleaved gates (2M floats)
#define OFF_WATT    2097152u                // fp32 [1024][1024] W_attnh top, transposed
#define OFF_HPRET   3145728u                // fp32 [1024][512]  Hpre TRANSPOSED
#define OFF_XIOU    3670016u                // fp32 [256][3072]
#define OFF_XF      4456448u                // fp32 [256][1024]
#define OFF_G       4718592u                // bf16 [512][4096]  G = H @ Wg
#define OFF_HT      5767168u                // fp32 [1024][512]  H transposed
#define OFF_HCOL    6291456u                // fp32 [1024]
#define OFF_SCORED  6297600u                // f64 [2][8][512] count-biased score copies, COPY-MAJOR (zeroed)
#define OFF_HLINE   6313984u                // u64 [128][8]: 8 packets {f32 h, u32 epoch} per block (zeroed)

// R23 score reduction = R20's verified geometry: 8 copies (1 per XCD),
// RMW depth 16, poll width 8. R22-B falsified the depth lever: 16 copies
// (depth 8, width 16) cost +170us -- poll width dominates settle depth.
// Copy x of element t gets 16 adds (blocks with b&7==x, one XCD).
// Settled = 16*BIAS32 + partial; de-bias SUBBIAS=2^36 (Sterbenz-exact).
#define BIAS32  4294967296.0                // 2^32
#define SUBBIAS (16.0 * 4294967296.0)       // 2^36
#define DONE_TH (16.0 * 4294967296.0 - 1073741824.0)   // 16*2^32 - 2^30

typedef __attribute__((ext_vector_type(8))) short short8;
typedef __attribute__((ext_vector_type(4))) float f32x4;

__device__ inline float fast_tanh(float v) {
    float x = fminf(fmaxf(v, -15.f), 15.f);
    float z = __expf(2.f * x);
    return (z - 1.f) / (z + 1.f);
}
__device__ inline float sigm(float v) { return 1.f / (1.f + __expf(-v)); }

__device__ inline float wave_red(float v) {
#pragma unroll
    for (int s = 32; s > 0; s >>= 1) v += __shfl_down(v, s, 64);
    return v;
}

__device__ __host__ inline unsigned short f2b(float f) {
    __hip_bfloat16 h = __float2bfloat16(f);
    return *(unsigned short*)&h;
}
__device__ inline float b2f(unsigned short u) {
    union { unsigned i; float f; } v; v.i = ((unsigned)u) << 16; return v.f;
}

// device-scope relaxed atomics
__device__ inline double gloadd(const double* p) {
    return __hip_atomic_load(p, __ATOMIC_RELAXED, __HIP_MEMORY_SCOPE_AGENT);
}
__device__ inline void gstored(double* p, double v) {
    __hip_atomic_store(p, v, __ATOMIC_RELAXED, __HIP_MEMORY_SCOPE_AGENT);
}
__device__ inline void gatomicd(double* p, double v) {
    __hip_atomic_fetch_add(p, v, __ATOMIC_RELAXED, __HIP_MEMORY_SCOPE_AGENT);
}
__device__ inline unsigned long long gloadu64(const unsigned long long* p) {
    return __hip_atomic_load(p, __ATOMIC_RELAXED, __HIP_MEMORY_SCOPE_AGENT);
}
__device__ inline void gstoreu64(unsigned long long* p, unsigned long long v) {
    __hip_atomic_store(p, v, __ATOMIC_RELAXED, __HIP_MEMORY_SCOPE_AGENT);
}

// -------- precompute kernels (R22 set, verified ~139us total) --------

__global__ void build_wg(const float* __restrict__ Wiouh, const float* __restrict__ Wfh,
                         unsigned short* __restrict__ Wgb) {
    int k = blockIdx.y;
    int g = blockIdx.x * 256 + threadIdx.x;
    unsigned a = f2b(Wiouh[k * 3072 + g]);
    unsigned b = f2b(Wiouh[k * 3072 + 1024 + g]);
    unsigned c = f2b(Wiouh[k * 3072 + 2048 + g]);
    unsigned d = f2b(Wfh[k * 1024 + g]);
    uint2 p; p.x = a | (b << 16); p.y = c | (d << 16);
    *(uint2*)(Wgb + (size_t)k * 4096 + 4 * g) = p;
}

__global__ void transpose_g(const float* __restrict__ src, float* __restrict__ dst,
                            int R, int C) {
    __shared__ float tile[32][33];
    int c = blockIdx.x * 32 + threadIdx.x;
    int r0 = blockIdx.y * 32;
    for (int i = threadIdx.y; i < 32; i += 8)
        tile[i][threadIdx.x] = src[(size_t)(r0 + i) * C + c];
    __syncthreads();
    int r = r0 + threadIdx.x;
    int c0 = blockIdx.x * 32;
    for (int i = threadIdx.y; i < 32; i += 8)
        dst[(size_t)(c0 + i) * R + r] = tile[threadIdx.x][i];
}

// colsum from HT (contiguous per-k rows), 32 blocks.
__global__ void colsum2_k(const float* __restrict__ HT, float* __restrict__ out) {
    int k = blockIdx.x * 32 + (threadIdx.x >> 3);
    int sub = threadIdx.x & 7;
    const float* row = HT + (size_t)k * 512 + sub * 64;
    float s = 0.f;
#pragma unroll
    for (int j = 0; j < 16; j++) {
        float4 v = *(const float4*)(row + j * 4);
        s += v.x + v.y + v.z + v.w;
    }
#pragma unroll
    for (int d = 4; d > 0; d >>= 1) s += __shfl_down(s, d, 8);
    if (sub == 0) out[k] = s;
}

// bf16-MFMA 64x64 tile body (verified R21). fp32->bf16 staging, fp32 acc.
#define MFMA_TILE_BODY(Bptr, LDB, NC0)                                         \
    for (int kk = 0; kk < 1024; kk += 32) {                                    \
        const float4 a0 = *(const float4*)(A + (size_t)(m0 + ar) * 1024 + kk + ak);      \
        const float4 a1 = *(const float4*)(A + (size_t)(m0 + ar) * 1024 + kk + ak + 4);  \
        short8 av;                                                             \
        av[0] = f2b(a0.x); av[1] = f2b(a0.y); av[2] = f2b(a0.z); av[3] = f2b(a0.w); \
        av[4] = f2b(a1.x); av[5] = f2b(a1.y); av[6] = f2b(a1.z); av[7] = f2b(a1.w); \
        short8 bv;                                                             \
        _Pragma("unroll")                                                      \
        for (int i = 0; i < 8; i++)                                            \
            bv[i] = f2b((Bptr)[(size_t)(kk + bk + i) * (LDB) + (NC0) + bn]);   \
        __syncthreads();                                                       \
        *(short8*)(As + ar * 40 + ak) = av;                                    \
        *(short8*)(Bs + bn * 40 + bk) = bv;                                    \
        __syncthreads();                                                       \
        const short8 af = *(const short8*)(As + (w * 16 + fr) * 40 + fk);      \
        _Pragma("unroll")                                                      \
        for (int c = 0; c < 4; c++) {                                          \
            const short8 bf = *(const short8*)(Bs + (c * 16 + fr) * 40 + fk);  \
            acc[c] = __builtin_amdgcn_mfma_f32_16x16x32_bf16(af, bf, acc[c], 0, 0, 0); \
        }                                                                      \
    }

// Fused inputs-GEMM: [X_iou | X_f] = inputs @ [W_ioux | W_fx] + biases.
__global__ __launch_bounds__(256) void gemm_x(
    const float* __restrict__ A, const float* __restrict__ Wioux,
    const float* __restrict__ Wfx, const float* __restrict__ bioux,
    const float* __restrict__ biouh, const float* __restrict__ bfx,
    const float* __restrict__ bfh, float* __restrict__ Xiou,
    float* __restrict__ Xf) {
    __shared__ unsigned short As[64 * 40];
    __shared__ unsigned short Bs[64 * 40];
    const int t = threadIdx.x;
    const int n0g = blockIdx.x * 64, m0 = blockIdx.y * 64;
    const int l = t & 63, w = t >> 6;
    const int fr = l & 15, fk = (l >> 4) * 8;
    const int ar = t >> 2, ak = (t & 3) * 8;
    const int bn = t >> 2, bk = (t & 3) * 8;
    const float* B; const float* c1; const float* c2; float* C;
    int ldb, ldc, nc0;
    if (n0g < 3072) { B = Wioux; ldb = 3072; nc0 = n0g; C = Xiou; ldc = 3072; c1 = bioux; c2 = biouh; }
    else            { B = Wfx;   ldb = 1024; nc0 = n0g - 3072; C = Xf; ldc = 1024; c1 = bfx; c2 = bfh; }
    f32x4 acc[4] = {};
    MFMA_TILE_BODY(B, ldb, nc0)
#pragma unroll
    for (int c = 0; c < 4; c++)
#pragma unroll
        for (int r = 0; r < 4; r++) {
            int m = m0 + w * 16 + (l >> 4) * 4 + r;
            int n = nc0 + c * 16 + (l & 15);
            C[(size_t)m * ldc + n] = acc[c][r] + c1[n] + c2[n];
        }
}

// Fused hiddn-GEMM: cols 0..3071 -> Gb (W_iouh), 3072..4095 -> Gb (W_fh,
// slot 3), 4096..5119 -> HpreT (W_attnh bottom, +bias, transposed).
__global__ __launch_bounds__(256) void gemm_h(
    const float* __restrict__ A, const float* __restrict__ Wiouh,
    const float* __restrict__ Wfh, const float* __restrict__ Wat,
    const float* __restrict__ battnh, unsigned short* __restrict__ Gb,
    float* __restrict__ HpreT) {
    __shared__ unsigned short As[64 * 40];
    __shared__ unsigned short Bs[64 * 40];
    const int t = threadIdx.x;
    const int n0g = blockIdx.x * 64, m0 = blockIdx.y * 64;
    const int l = t & 63, w = t >> 6;
    const int fr = l & 15, fk = (l >> 4) * 8;
    const int ar = t >> 2, ak = (t & 3) * 8;
    const int bn = t >> 2, bk = (t & 3) * 8;
    const float* B; int ldb, nc0, mode;
    if (n0g < 3072)      { B = Wiouh; ldb = 3072; nc0 = n0g; mode = 0; }
    else if (n0g < 4096) { B = Wfh;   ldb = 1024; nc0 = n0g - 3072; mode = 1; }
    else                 { B = Wat;   ldb = 1024; nc0 = n0g - 4096; mode = 2; }
    f32x4 acc[4] = {};
    MFMA_TILE_BODY(B, ldb, nc0)
#pragma unroll
    for (int c = 0; c < 4; c++)
#pragma unroll
        for (int r = 0; r < 4; r++) {
            int m = m0 + w * 16 + (l >> 4) * 4 + r;
            int n = nc0 + c * 16 + (l & 15);
            float v = acc[c][r];
            if (mode == 0) {
                int cp = 4 * (n & 1023) + (n >> 10);
                Gb[(size_t)m * 4096 + cp] = f2b(v);
            } else if (mode == 1) {
                Gb[(size_t)m * 4096 + 4 * n + 3] = f2b(v);
            } else {
                HpreT[(size_t)n * 512 + m] = v + battnh[n];
            }
        }
}

__device__ inline float sum8(const float* s) {
    return s[0] + s[1] + s[2] + s[3] + s[4] + s[5] + s[6] + s[7];
}

// -------- persistent recurrent kernel --------
// R23 = R20's verified recurrent (1296us: 8 score copies, depth 16,
// poll width 8) + R22's hcw prologue fold (hcolw launch eliminated).
__global__ __launch_bounds__(NTHR, 2) void recurrent(
    const unsigned short* __restrict__ Wgb, const float* __restrict__ WatT,
    const float* __restrict__ HpreT, const float* __restrict__ HT,
    const float* __restrict__ Hcol, const unsigned short* __restrict__ Gb,
    const float* __restrict__ X_iou, const float* __restrict__ X_f,
    const float* __restrict__ Wa,
    unsigned long long* hline, double* scored, float* out) {

    const int b = blockIdx.x, t = threadIdx.x;
    const int x = b & 7, y = b >> 3;          // y in [0,16)
    const int g_col = x * 128 + y * 8;        // block's 8 output/attention cols
    const int j0 = x * 512 + y * 32;          // block's 32 interleaved gate cols
    float creg = 0.f;                          // cell state (threads t<8)
    __shared__ float smem[2648];
    float* hs   = smem;          // 1056 padded h (current)
    float* le   = smem + 1056;   // 512 e
    float* red  = smem + 1568;   // [16][32] s1 partials (written in X overlap)
    float* red2 = smem + 2080;   // [16][32] s2 partials
    float* sred = smem + 2592;   // 8  (S partials, 1/wave)
    float* sred2= smem + 2600;   // 8  (P per col, 1/wave)
    float* dotb = smem + 2608;   // 32
    float* attr = smem + 2640;   // 8  (att_v per col, 1/wave)

    const int jt = t & 31, kq = t >> 5;       // gates: 16 k-groups x 32 cols
    const int li = t & 63, tr = t >> 6;       // lane, wave id (0..7)
    const int tl = t & 127, hi = t >> 7;      // h-poll: 4 thr/line, 2 packets

    // ---- hoist step-invariant loads into registers ----
    float wregf[64];
#pragma unroll
    for (int i = 0; i < 64; i++)
        wregf[i] = b2f(Wgb[(size_t)(kq * 64 + i) * 4096 + j0 + jt]);
    float gregf[32];
#pragma unroll
    for (int i = 0; i < 32; i++)
        gregf[i] = b2f(Gb[(size_t)(kq * 32 + i) * 4096 + j0 + jt]);
    float watreg[16];
#pragma unroll
    for (int i = 0; i < 16; i++)
        watreg[i] = WatT[(size_t)(g_col + tr) * 1024 + i * 64 + li];
    float htr[8], hpr[8], wa8[8];
#pragma unroll
    for (int i = 0; i < 8; i++)
        htr[i] = HT[(size_t)(g_col + tr) * 512 + li + 64 * i];
#pragma unroll
    for (int c = 0; c < 8; c++) {
        hpr[c] = HpreT[(size_t)(g_col + c) * 512 + t];
        wa8[c] = Wa[g_col + c];
    }
    const float hcolg = (t < 8) ? Hcol[g_col + t] : 0.f;

    // ---- prologue: hcw = sum_k Hcol[k] * Wgb[k][j0+jt] from wregf ----
    // (replaces the hcolw kernel; Hcol staged in hs, reduced via red)
    hs[t + (t >> 5)] = Hcol[t];
    { int k2 = t + 512; hs[k2 + (k2 >> 5)] = Hcol[t + 512]; }
    __syncthreads();
    {
        float hp = 0.f;
#pragma unroll
        for (int i = 0; i < 64; i++) {
            int k = kq * 64 + i;
            hp = fmaf(hs[k + (k >> 5)], wregf[i], hp);
        }
        red[kq * 32 + jt] = hp;
    }
    __syncthreads();
    float hcw = 0.f;
    if (t < 32) {
#pragma unroll
        for (int q = 0; q < 16; q++) hcw += red[q * 32 + t];
    }
    __syncthreads();
    // prime: s1 partials = 0 for step 0 (hs fully rewritten in X(0))
    red[kq * 32 + jt] = 0.f;

    for (int st = 0; st < T_STEPS; st++) {
        // ---- Y: e (poll 8 strided copies) + gates + h packets + out ----
        float xi0 = 0.f, xi1 = 0.f, xi2 = 0.f, xf0 = 0.f;
        if (t < 8) {                      // issued before poll: latency hidden
            int g = g_col + t;
            xi0 = X_iou[(size_t)st * 3072 + g];
            xi1 = X_iou[(size_t)st * 3072 + 1024 + g];
            xi2 = X_iou[(size_t)st * 3072 + 2048 + g];
            xf0 = X_f[(size_t)st * 1024 + g];
        }
        float sc = 0.f;
        if (st > 0) {
            const double* sp = scored + (size_t)((st + 1) & 1) * 4096 + t;
            double vv[8];
            for (;;) {
                bool ok = true;
#pragma unroll
                for (int c = 0; c < 8; c++) {
                    vv[c] = gloadd(sp + c * 512);
                    ok = ok && (vv[c] > DONE_TH);
                }
                if (ok) break;
                __builtin_amdgcn_s_sleep(1);
            }
            double accd = 0.0;
#pragma unroll
            for (int c = 0; c < 8; c++) accd += (vv[c] - SUBBIAS);
            sc = (float)accd;
        }
        float evv = __expf(sc);
        le[t] = evv;
        float sv = wave_red(evv);
        if ((t & 63) == 0) sred[t >> 6] = sv;
        __syncthreads();                       // #1
        // s2 (G-correction) from registers: rows kq*32+i
        float a2 = 0.f;
#pragma unroll
        for (int i = 0; i < 32; i++)
            a2 = fmaf(le[kq * 32 + i], gregf[i], a2);
        red2[kq * 32 + jt] = a2;
        // P for block's 8 out-cols: wave tr owns col g_col+tr
        float pp = 0.f;
#pragma unroll
        for (int i = 0; i < 8; i++)
            pp = fmaf(le[li + 64 * i], htr[i], pp);
        pp = wave_red(pp);
        if ((t & 63) == 0) sred2[t >> 6] = pp;
        __syncthreads();                       // #2
        if (t < 32) {                          // wave-0 writes dotb...
            float s1 = 0.f, s2 = 0.f;
#pragma unroll
            for (int q = 0; q < 16; q++) { s1 += red[q * 32 + t]; s2 += red2[q * 32 + t]; }
            float S = sum8(sred);
            float invS = (st == 0) ? 0.f : 1.f / S;
            float hw = (st == 0) ? 0.f : hcw;
            dotb[t] = s1 + hw - invS * s2;
        }
        if (t < 8) {                           // ...read also wave-0: in-order LDS
            int g = g_col + t;
            if (st > 0) {
                float S = sum8(sred);
                float P = sred2[t];
                out[(size_t)(st - 1) * 1024 + g] =
                    hcolg + hs[g + (g >> 5)] - P / S;
            }
            float di = dotb[t * 4 + 0] + xi0;
            float doo = dotb[t * 4 + 1] + xi1;
            float du = dotb[t * 4 + 2] + xi2;
            float df = dotb[t * 4 + 3] + xf0;
            float ig = sigm(di), og = sigm(doo), fg = sigm(df);
            float ug = fast_tanh(du);
            creg = ig * ug + fg * creg;
            float hv = og * fast_tanh(creg);
            // fused payload+flag: one 8B single-copy-atomic packet
            unsigned long long pkt =
                ((unsigned long long)(unsigned)(st + 1) << 32) | __float_as_uint(hv);
            gstoreu64(hline + (size_t)b * 8 + t, pkt);
        }
        __syncthreads();                       // #4: hs rewritten in X below

        // ---- X: poll-with-payload h -> LDS, att_v, biased f64 adds ----
        {
            const unsigned long long* lp = hline + (size_t)tl * 8 + hi * 2;
            const unsigned tgt = (unsigned)(st + 1);
            unsigned long long u0, u1;
            for (;;) {
                u0 = gloadu64(lp);
                u1 = gloadu64(lp + 1);
                if ((unsigned)(u0 >> 32) >= tgt && (unsigned)(u1 >> 32) >= tgt) break;
                __builtin_amdgcn_s_sleep(1);
            }
            int gc = (tl & 7) * 128 + (tl >> 3) * 8 + hi * 2;
            union { unsigned u; float f; } c0, c1;
            c0.u = (unsigned)u0; c1.u = (unsigned)u1;
            hs[gc + (gc >> 5)] = c0.f;
            int g1 = gc + 1; hs[g1 + (g1 >> 5)] = c1.f;
        }
        __syncthreads();                       // #5: hs ready AND all 128 lines
                                               // verified >= st+1 block-wide
        // zero the buffer all Y(st) consumed: safe after #5 (every block has
        // passed its Y(st) reads, proven by the 128 epochs). 32 doubles per
        // block cover the 4096-double buffer exactly once.
        if (t < 32)
            gstored(scored + (size_t)((st + 1) & 1) * 4096 + (size_t)b * 32 + t, 0.0);
        {
            // att_v: wave tr computes col g_col+tr (16 fma/lane from hs)
            float acc = 0.f;
#pragma unroll
            for (int i = 0; i < 16; i++) {
                int k = i * 64 + li;
                acc = fmaf(watreg[i], hs[k + (k >> 5)], acc);
            }
            acc = wave_red(acc);
            if ((t & 63) == 0) attr[t >> 6] = acc;
            __syncthreads();                   // #6 (implicit vmcnt(0): zeroes)
            float ps = 0.f;
#pragma unroll
            for (int c = 0; c < 8; c++)
                ps = fmaf(wa8[c], fast_tanh(hpr[c] + attr[c]), ps);
            __asm__ volatile("" ::: "memory");
            __builtin_amdgcn_s_waitcnt(0);     // own zero-store drained first
            gatomicd(scored + (size_t)(st & 1) * 4096 + x * 512 + t,
                     (double)ps + BIAS32);
        }
        // s1 overlap for next step's gates (runs under the exchange latency)
        {
            float a = 0.f;
#pragma unroll
            for (int i = 0; i < 64; i++) {
                int k = kq * 64 + i;
                a = fmaf(hs[k + (k >> 5)], wregf[i], a);
            }
            red[kq * 32 + jt] = a;
        }
    }

    // ---- Epilogue: out[T-1] (Y(T) without gates) ----
    {
        const double* sp = scored + (size_t)((T_STEPS + 1) & 1) * 4096 + t;
        double vv[8];
        for (;;) {
            bool ok = true;
#pragma unroll
            for (int c = 0; c < 8; c++) {
                vv[c] = gloadd(sp + c * 512);
                ok = ok && (vv[c] > DONE_TH);
            }
            if (ok) break;
            __builtin_amdgcn_s_sleep(1);
        }
        double accd = 0.0;
#pragma unroll
        for (int c = 0; c < 8; c++) accd += (vv[c] - SUBBIAS);
        float evv = __expf((float)accd);
        le[t] = evv;
        float sv = wave_red(evv);
        if ((t & 63) == 0) sred[t >> 6] = sv;
        __syncthreads();
        float pp = 0.f;
#pragma unroll
        for (int i = 0; i < 8; i++)
            pp = fmaf(le[li + 64 * i], htr[i], pp);
        pp = wave_red(pp);
        if ((t & 63) == 0) sred2[t >> 6] = pp;
        __syncthreads();
        if (t < 8) {
            int g = g_col + t;
            float S = sum8(sred);
            float P = sred2[t];
            out[(size_t)(T_STEPS - 1) * 1024 + g] =
                hcolg + hs[g + (g >> 5)] - P / S;   // hs = h(T-1) from X(T-1)
        }
    }
}

extern "C" void kernel_launch(void* const* d_in, const int* in_sizes, int n_in,
                              void* d_out, int out_size, void* d_ws, size_t ws_size,
                              hipStream_t stream) {
    const float* inputs  = (const float*)d_in[0];
    const float* hiddn   = (const float*)d_in[1];
    const float* W_ioux  = (const float*)d_in[2];
    const float* b_ioux  = (const float*)d_in[3];
    const float* W_iouh  = (const float*)d_in[4];
    const float* b_iouh  = (const float*)d_in[5];
    const float* W_fx    = (const float*)d_in[6];
    const float* b_fx    = (const float*)d_in[7];
    const float* W_fh    = (const float*)d_in[8];
    const float* b_fh    = (const float*)d_in[9];
    const float* Wa      = (const float*)d_in[10];
    const float* W_attnh = (const float*)d_in[11];
    const float* b_attnh = (const float*)d_in[12];

    float* ws = (float*)d_ws;
    unsigned short* Wgb = (unsigned short*)(ws + OFF_WGB);
    float* WatT  = ws + OFF_WATT;
    float* HpreT = ws + OFF_HPRET;
    float* X_iou = ws + OFF_XIOU;
    float* X_f   = ws + OFF_XF;
    unsigned short* Gb = (unsigned short*)(ws + OFF_G);
    float* HT    = ws + OFF_HT;
    float* Hcol  = ws + OFF_HCOL;
    double* scored = (double*)(ws + OFF_SCORED);
    unsigned long long* hline = (unsigned long long*)(ws + OFF_HLINE);
    float* out   = (float*)d_out;

    // zero score copies (2x4096 f64 = 16384 floats) + hline (2048 floats)
    hipMemsetAsync(ws + OFF_SCORED, 0, (16384 + 2048) * sizeof(float), stream);

    build_wg<<<dim3(4, 1024), 256, 0, stream>>>(W_iouh, W_fh, Wgb);
    transpose_g<<<dim3(32, 32), dim3(32, 8), 0, stream>>>(W_attnh, WatT, 1024, 1024);
    transpose_g<<<dim3(32, 16), dim3(32, 8), 0, stream>>>(hiddn, HT, 512, 1024);
    colsum2_k<<<32, 256, 0, stream>>>(HT, Hcol);
    gemm_x<<<dim3(64, 4), 256, 0, stream>>>(inputs, W_ioux, W_fx, b_ioux, b_iouh,
                                            b_fx, b_fh, X_iou, X_f);
    gemm_h<<<dim3(80, 8), 256, 0, stream>>>(hiddn, W_iouh, W_fh,
                                            W_attnh + 1024 * 1024, b_attnh, Gb, HpreT);

    recurrent<<<GRID, NTHR, 0, stream>>>(Wgb, WatT, HpreT, HT, Hcol, Gb,
                                         X_iou, X_f, Wa, hline, scored, out);
}

// Round 12
// 1406.087 us; speedup vs baseline: 1.1418x; 1.0207x over previous
//
#include <hip/hip_runtime.h>
#include <hip/hip_bf16.h>

// ---------------- sizes ----------------
#define T_STEPS 256
#define MDIM 1024
#define MROWS 512
#define NBLK 128
#define GRID NBLK
#define NTHR 512

// ws float offsets
#define OFF_WGB     0u                      // bf16 [1024][4096] interleaved gates (2M floats)
#define OFF_WATT    2097152u                // fp32 [1024][1024] W_attnh top, transposed
#define OFF_HPRET   3145728u                // fp32 [1024][512]  Hpre TRANSPOSED
#define OFF_XIOU    3670016u                // fp32 [256][3072]
#define OFF_XF      4456448u                // fp32 [256][1024]
#define OFF_G       4718592u                // bf16 [512][4096]  G = H @ Wg
#define OFF_HT      5767168u                // fp32 [1024][512]  H transposed
#define OFF_HCOL    6291456u                // fp32 [1024] (zeroed; atomic-accumulated)
#define OFF_SCORED  6297600u                // f64 [2][8][512] count-biased score copies, COPY-MAJOR (zeroed)
#define OFF_HLINE   6313984u                // u64 [128][8]: 8 packets {f32 h, u32 epoch} per block (zeroed)

// R24 = R23's verified recurrent (1271us) + precompute consolidation:
// 9 -> 4 dispatches (prep + gemm_xh), gemm_h B read as bf16 from Wgb.
// Score exchange: 8 copies (1/XCD), RMW depth 16, poll width 8 --
// measured local optimum (R22-B falsified depth-8/width-16).
#define BIAS32  4294967296.0                // 2^32
#define SUBBIAS (16.0 * 4294967296.0)       // 2^36
#define DONE_TH (16.0 * 4294967296.0 - 1073741824.0)   // 16*2^32 - 2^30

typedef __attribute__((ext_vector_type(8))) short short8;
typedef __attribute__((ext_vector_type(4))) float f32x4;

__device__ inline float fast_tanh(float v) {
    float x = fminf(fmaxf(v, -15.f), 15.f);
    float z = __expf(2.f * x);
    return (z - 1.f) / (z + 1.f);
}
__device__ inline float sigm(float v) { return 1.f / (1.f + __expf(-v)); }

__device__ inline float wave_red(float v) {
#pragma unroll
    for (int s = 32; s > 0; s >>= 1) v += __shfl_down(v, s, 64);
    return v;
}

__device__ __host__ inline unsigned short f2b(float f) {
    __hip_bfloat16 h = __float2bfloat16(f);
    return *(unsigned short*)&h;
}
__device__ inline float b2f(unsigned short u) {
    union { unsigned i; float f; } v; v.i = ((unsigned)u) << 16; return v.f;
}

// device-scope relaxed atomics
__device__ inline double gloadd(const double* p) {
    return __hip_atomic_load(p, __ATOMIC_RELAXED, __HIP_MEMORY_SCOPE_AGENT);
}
__device__ inline void gstored(double* p, double v) {
    __hip_atomic_store(p, v, __ATOMIC_RELAXED, __HIP_MEMORY_SCOPE_AGENT);
}
__device__ inline void gatomicd(double* p, double v) {
    __hip_atomic_fetch_add(p, v, __ATOMIC_RELAXED, __HIP_MEMORY_SCOPE_AGENT);
}
__device__ inline unsigned long long gloadu64(const unsigned long long* p) {
    return __hip_atomic_load(p, __ATOMIC_RELAXED, __HIP_MEMORY_SCOPE_AGENT);
}
__device__ inline void gstoreu64(unsigned long long* p, unsigned long long v) {
    __hip_atomic_store(p, v, __ATOMIC_RELAXED, __HIP_MEMORY_SCOPE_AGENT);
}

// -------- prep: build_wg || WatT-transpose || HT-transpose || colsum --------
// Block ranges: [0,4096) build_wg; [4096,5120) WatT tiles; [5120,5632) HT
// tiles; [5632,5664) colsum partials (f32 atomics into zeroed Hcol).
__global__ __launch_bounds__(256) void prep(
    const float* __restrict__ Wiouh, const float* __restrict__ Wfh,
    unsigned short* __restrict__ Wgb, const float* __restrict__ Wat_top,
    float* __restrict__ WatT, const float* __restrict__ hiddn,
    float* __restrict__ HT, float* __restrict__ Hcol) {
    __shared__ float tile[32][33];
    const int i = blockIdx.x, t = threadIdx.x;
    if (i < 4096) {
        int k = i >> 2;
        int g = (i & 3) * 256 + t;
        unsigned a = f2b(Wiouh[(size_t)k * 3072 + g]);
        unsigned b = f2b(Wiouh[(size_t)k * 3072 + 1024 + g]);
        unsigned c = f2b(Wiouh[(size_t)k * 3072 + 2048 + g]);
        unsigned d = f2b(Wfh[(size_t)k * 1024 + g]);
        uint2 p; p.x = a | (b << 16); p.y = c | (d << 16);
        *(uint2*)(Wgb + (size_t)k * 4096 + 4 * g) = p;
    } else if (i < 5120) {                    // WatT: [1024][1024] transpose
        int ii = i - 4096;
        int bx = ii & 31, by = ii >> 5;
        int tx = t & 31, ty = t >> 5;
        int c = bx * 32 + tx, r0 = by * 32;
        for (int j = ty; j < 32; j += 8)
            tile[j][tx] = Wat_top[(size_t)(r0 + j) * 1024 + c];
        __syncthreads();
        int r = r0 + tx, c0 = bx * 32;
        for (int j = ty; j < 32; j += 8)
            WatT[(size_t)(c0 + j) * 1024 + r] = tile[tx][j];
    } else if (i < 5632) {                    // HT: hiddn [512][1024] -> [1024][512]
        int ii = i - 5120;
        int bx = ii & 31, by = ii >> 5;       // by in [0,16)
        int tx = t & 31, ty = t >> 5;
        int c = bx * 32 + tx, r0 = by * 32;
        for (int j = ty; j < 32; j += 8)
            tile[j][tx] = hiddn[(size_t)(r0 + j) * 1024 + c];
        __syncthreads();
        int r = r0 + tx, c0 = bx * 32;
        for (int j = ty; j < 32; j += 8)
            HT[(size_t)(c0 + j) * 512 + r] = tile[tx][j];
    } else {                                  // colsum: 32 blocks x 64-row partials
        int ii = i - 5632;
        int k = (ii & 3) * 256 + t;
        int r0 = (ii >> 2) * 64;
        float s = 0.f;
#pragma unroll 8
        for (int r = 0; r < 64; r++) s += hiddn[(size_t)(r0 + r) * 1024 + k];
        atomicAdd(Hcol + k, s);
    }
}

// bf16-MFMA 64x64 tile body (verified R21). fp32->bf16 staging, fp32 acc.
#define MFMA_TILE_BODY(Bptr, LDB, NC0)                                         \
    for (int kk = 0; kk < 1024; kk += 32) {                                    \
        const float4 a0 = *(const float4*)(A + (size_t)(m0 + ar) * 1024 + kk + ak);      \
        const float4 a1 = *(const float4*)(A + (size_t)(m0 + ar) * 1024 + kk + ak + 4);  \
        short8 av;                                                             \
        av[0] = f2b(a0.x); av[1] = f2b(a0.y); av[2] = f2b(a0.z); av[3] = f2b(a0.w); \
        av[4] = f2b(a1.x); av[5] = f2b(a1.y); av[6] = f2b(a1.z); av[7] = f2b(a1.w); \
        short8 bv;                                                             \
        _Pragma("unroll")                                                      \
        for (int i2 = 0; i2 < 8; i2++)                                         \
            bv[i2] = f2b((Bptr)[(size_t)(kk + bk + i2) * (LDB) + (NC0) + bn]); \
        __syncthreads();                                                       \
        *(short8*)(As + ar * 40 + ak) = av;                                    \
        *(short8*)(Bs + bn * 40 + bk) = bv;                                    \
        __syncthreads();                                                       \
        const short8 af = *(const short8*)(As + (w * 16 + fr) * 40 + fk);      \
        _Pragma("unroll")                                                      \
        for (int c = 0; c < 4; c++) {                                          \
            const short8 bf = *(const short8*)(Bs + (c * 16 + fr) * 40 + fk);  \
            acc[c] = __builtin_amdgcn_mfma_f32_16x16x32_bf16(af, bf, acc[c], 0, 0, 0); \
        }                                                                      \
    }

// Fused GEMMs, one kernel, 896 blocks:
//  [0,256):   gemm_x  -- [X_iou | X_f] = inputs @ [W_ioux | W_fx] + biases
//  [256,896): gemm_h  -- cols<4096: Gb = hiddn @ [W_iouh|W_fh] with B READ
//             AS BF16 FROM Wgb (cp = 4*(n&1023)+(n>>10) covers both: slots
//             0-2 = W_iouh thirds, slot 3 = W_fh -- same formula as the Gb
//             output interleave); cols>=4096: HpreT = (hiddn @ Wat_bot + b)^T
__global__ __launch_bounds__(256) void gemm_xh(
    const float* __restrict__ inputs, const float* __restrict__ Wioux,
    const float* __restrict__ Wfx, const float* __restrict__ bioux,
    const float* __restrict__ biouh, const float* __restrict__ bfx,
    const float* __restrict__ bfh, float* __restrict__ Xiou,
    float* __restrict__ Xf, const float* __restrict__ hiddn,
    const unsigned short* __restrict__ Wgb, const float* __restrict__ Wat,
    const float* __restrict__ battnh, unsigned short* __restrict__ Gb,
    float* __restrict__ HpreT) {
    __shared__ unsigned short As[64 * 40];
    __shared__ unsigned short Bs[64 * 40];
    const int t = threadIdx.x, blk = blockIdx.x;
    const int l = t & 63, w = t >> 6;
    const int fr = l & 15, fk = (l >> 4) * 8;
    const int ar = t >> 2, ak = (t & 3) * 8;
    const int bn = t >> 2, bk = (t & 3) * 8;
    f32x4 acc[4] = {};
    if (blk < 256) {
        // ---- gemm_x ----
        const int n0g = (blk & 63) * 64, m0 = (blk >> 6) * 64;
        const float* A = inputs;
        const float* B; const float* c1; const float* c2; float* C;
        int ldb, ldc, nc0;
        if (n0g < 3072) { B = Wioux; ldb = 3072; nc0 = n0g; C = Xiou; ldc = 3072; c1 = bioux; c2 = biouh; }
        else            { B = Wfx;   ldb = 1024; nc0 = n0g - 3072; C = Xf; ldc = 1024; c1 = bfx; c2 = bfh; }
        MFMA_TILE_BODY(B, ldb, nc0)
#pragma unroll
        for (int c = 0; c < 4; c++)
#pragma unroll
            for (int r = 0; r < 4; r++) {
                int m = m0 + w * 16 + (l >> 4) * 4 + r;
                int n = nc0 + c * 16 + (l & 15);
                C[(size_t)m * ldc + n] = acc[c][r] + c1[n] + c2[n];
            }
    } else {
        const int ii = blk - 256;
        const int n0g = (ii % 80) * 64, m0 = (ii / 80) * 64;
        const float* A = hiddn;
        if (n0g < 4096) {
            // B from Wgb (bf16): no per-iter converts, half the B bytes
            const int cp = 4 * ((n0g + bn) & 1023) + ((n0g + bn) >> 10);
            for (int kk = 0; kk < 1024; kk += 32) {
                const float4 a0 = *(const float4*)(A + (size_t)(m0 + ar) * 1024 + kk + ak);
                const float4 a1 = *(const float4*)(A + (size_t)(m0 + ar) * 1024 + kk + ak + 4);
                short8 av;
                av[0] = f2b(a0.x); av[1] = f2b(a0.y); av[2] = f2b(a0.z); av[3] = f2b(a0.w);
                av[4] = f2b(a1.x); av[5] = f2b(a1.y); av[6] = f2b(a1.z); av[7] = f2b(a1.w);
                short8 bv;
#pragma unroll
                for (int i2 = 0; i2 < 8; i2++)
                    bv[i2] = (short)Wgb[(size_t)(kk + bk + i2) * 4096 + cp];
                __syncthreads();
                *(short8*)(As + ar * 40 + ak) = av;
                *(short8*)(Bs + bn * 40 + bk) = bv;
                __syncthreads();
                const short8 af = *(const short8*)(As + (w * 16 + fr) * 40 + fk);
#pragma unroll
                for (int c = 0; c < 4; c++) {
                    const short8 bf = *(const short8*)(Bs + (c * 16 + fr) * 40 + fk);
                    acc[c] = __builtin_amdgcn_mfma_f32_16x16x32_bf16(af, bf, acc[c], 0, 0, 0);
                }
            }
#pragma unroll
            for (int c = 0; c < 4; c++)
#pragma unroll
                for (int r = 0; r < 4; r++) {
                    int m = m0 + w * 16 + (l >> 4) * 4 + r;
                    int n = n0g + c * 16 + (l & 15);
                    int cpo = 4 * (n & 1023) + (n >> 10);
                    Gb[(size_t)m * 4096 + cpo] = f2b(acc[c][r]);
                }
        } else {
            const int nc0 = n0g - 4096;
            MFMA_TILE_BODY(Wat, 1024, nc0)
#pragma unroll
            for (int c = 0; c < 4; c++)
#pragma unroll
                for (int r = 0; r < 4; r++) {
                    int m = m0 + w * 16 + (l >> 4) * 4 + r;
                    int n = nc0 + c * 16 + (l & 15);
                    HpreT[(size_t)n * 512 + m] = acc[c][r] + battnh[n];
                }
        }
    }
}

__device__ inline float sum8(const float* s) {
    return s[0] + s[1] + s[2] + s[3] + s[4] + s[5] + s[6] + s[7];
}

// -------- persistent recurrent kernel (R23, verified 1271us, UNCHANGED) --------
__global__ __launch_bounds__(NTHR, 2) void recurrent(
    const unsigned short* __restrict__ Wgb, const float* __restrict__ WatT,
    const float* __restrict__ HpreT, const float* __restrict__ HT,
    const float* __restrict__ Hcol, const unsigned short* __restrict__ Gb,
    const float* __restrict__ X_iou, const float* __restrict__ X_f,
    const float* __restrict__ Wa,
    unsigned long long* hline, double* scored, float* out) {

    const int b = blockIdx.x, t = threadIdx.x;
    const int x = b & 7, y = b >> 3;          // y in [0,16)
    const int g_col = x * 128 + y * 8;        // block's 8 output/attention cols
    const int j0 = x * 512 + y * 32;          // block's 32 interleaved gate cols
    float creg = 0.f;                          // cell state (threads t<8)
    __shared__ float smem[2648];
    float* hs   = smem;          // 1056 padded h (current)
    float* le   = smem + 1056;   // 512 e
    float* red  = smem + 1568;   // [16][32] s1 partials (written in X overlap)
    float* red2 = smem + 2080;   // [16][32] s2 partials
    float* sred = smem + 2592;   // 8  (S partials, 1/wave)
    float* sred2= smem + 2600;   // 8  (P per col, 1/wave)
    float* dotb = smem + 2608;   // 32
    float* attr = smem + 2640;   // 8  (att_v per col, 1/wave)

    const int jt = t & 31, kq = t >> 5;       // gates: 16 k-groups x 32 cols
    const int li = t & 63, tr = t >> 6;       // lane, wave id (0..7)
    const int tl = t & 127, hi = t >> 7;      // h-poll: 4 thr/line, 2 packets

    // ---- hoist step-invariant loads into registers ----
    float wregf[64];
#pragma unroll
    for (int i = 0; i < 64; i++)
        wregf[i] = b2f(Wgb[(size_t)(kq * 64 + i) * 4096 + j0 + jt]);
    float gregf[32];
#pragma unroll
    for (int i = 0; i < 32; i++)
        gregf[i] = b2f(Gb[(size_t)(kq * 32 + i) * 4096 + j0 + jt]);
    float watreg[16];
#pragma unroll
    for (int i = 0; i < 16; i++)
        watreg[i] = WatT[(size_t)(g_col + tr) * 1024 + i * 64 + li];
    float htr[8], hpr[8], wa8[8];
#pragma unroll
    for (int i = 0; i < 8; i++)
        htr[i] = HT[(size_t)(g_col + tr) * 512 + li + 64 * i];
#pragma unroll
    for (int c = 0; c < 8; c++) {
        hpr[c] = HpreT[(size_t)(g_col + c) * 512 + t];
        wa8[c] = Wa[g_col + c];
    }
    const float hcolg = (t < 8) ? Hcol[g_col + t] : 0.f;

    // ---- prologue: hcw = sum_k Hcol[k] * Wgb[k][j0+jt] from wregf ----
    hs[t + (t >> 5)] = Hcol[t];
    { int k2 = t + 512; hs[k2 + (k2 >> 5)] = Hcol[t + 512]; }
    __syncthreads();
    {
        float hp = 0.f;
#pragma unroll
        for (int i = 0; i < 64; i++) {
            int k = kq * 64 + i;
            hp = fmaf(hs[k + (k >> 5)], wregf[i], hp);
        }
        red[kq * 32 + jt] = hp;
    }
    __syncthreads();
    float hcw = 0.f;
    if (t < 32) {
#pragma unroll
        for (int q = 0; q < 16; q++) hcw += red[q * 32 + t];
    }
    __syncthreads();
    // prime: s1 partials = 0 for step 0 (hs fully rewritten in X(0))
    red[kq * 32 + jt] = 0.f;

    for (int st = 0; st < T_STEPS; st++) {
        // ---- Y: e (poll 8 strided copies) + gates + h packets + out ----
        float xi0 = 0.f, xi1 = 0.f, xi2 = 0.f, xf0 = 0.f;
        if (t < 8) {                      // issued before poll: latency hidden
            int g = g_col + t;
            xi0 = X_iou[(size_t)st * 3072 + g];
            xi1 = X_iou[(size_t)st * 3072 + 1024 + g];
            xi2 = X_iou[(size_t)st * 3072 + 2048 + g];
            xf0 = X_f[(size_t)st * 1024 + g];
        }
        float sc = 0.f;
        if (st > 0) {
            const double* sp = scored + (size_t)((st + 1) & 1) * 4096 + t;
            double vv[8];
            for (;;) {
                bool ok = true;
#pragma unroll
                for (int c = 0; c < 8; c++) {
                    vv[c] = gloadd(sp + c * 512);
                    ok = ok && (vv[c] > DONE_TH);
                }
                if (ok) break;
                __builtin_amdgcn_s_sleep(1);
            }
            double accd = 0.0;
#pragma unroll
            for (int c = 0; c < 8; c++) accd += (vv[c] - SUBBIAS);
            sc = (float)accd;
        }
        float evv = __expf(sc);
        le[t] = evv;
        float sv = wave_red(evv);
        if ((t & 63) == 0) sred[t >> 6] = sv;
        __syncthreads();                       // #1
        // s2 (G-correction) from registers: rows kq*32+i
        float a2 = 0.f;
#pragma unroll
        for (int i = 0; i < 32; i++)
            a2 = fmaf(le[kq * 32 + i], gregf[i], a2);
        red2[kq * 32 + jt] = a2;
        // P for block's 8 out-cols: wave tr owns col g_col+tr
        float pp = 0.f;
#pragma unroll
        for (int i = 0; i < 8; i++)
            pp = fmaf(le[li + 64 * i], htr[i], pp);
        pp = wave_red(pp);
        if ((t & 63) == 0) sred2[t >> 6] = pp;
        __syncthreads();                       // #2
        if (t < 32) {                          // wave-0 writes dotb...
            float s1 = 0.f, s2 = 0.f;
#pragma unroll
            for (int q = 0; q < 16; q++) { s1 += red[q * 32 + t]; s2 += red2[q * 32 + t]; }
            float S = sum8(sred);
            float invS = (st == 0) ? 0.f : 1.f / S;
            float hw = (st == 0) ? 0.f : hcw;
            dotb[t] = s1 + hw - invS * s2;
        }
        if (t < 8) {                           // ...read also wave-0: in-order LDS
            int g = g_col + t;
            if (st > 0) {
                float S = sum8(sred);
                float P = sred2[t];
                out[(size_t)(st - 1) * 1024 + g] =
                    hcolg + hs[g + (g >> 5)] - P / S;
            }
            float di = dotb[t * 4 + 0] + xi0;
            float doo = dotb[t * 4 + 1] + xi1;
            float du = dotb[t * 4 + 2] + xi2;
            float df = dotb[t * 4 + 3] + xf0;
            float ig = sigm(di), og = sigm(doo), fg = sigm(df);
            float ug = fast_tanh(du);
            creg = ig * ug + fg * creg;
            float hv = og * fast_tanh(creg);
            // fused payload+flag: one 8B single-copy-atomic packet
            unsigned long long pkt =
                ((unsigned long long)(unsigned)(st + 1) << 32) | __float_as_uint(hv);
            gstoreu64(hline + (size_t)b * 8 + t, pkt);
        }
        __syncthreads();                       // #4: hs rewritten in X below

        // ---- X: poll-with-payload h -> LDS, att_v, biased f64 adds ----
        {
            const unsigned long long* lp = hline + (size_t)tl * 8 + hi * 2;
            const unsigned tgt = (unsigned)(st + 1);
            unsigned long long u0, u1;
            for (;;) {
                u0 = gloadu64(lp);
                u1 = gloadu64(lp + 1);
                if ((unsigned)(u0 >> 32) >= tgt && (unsigned)(u1 >> 32) >= tgt) break;
                __builtin_amdgcn_s_sleep(1);
            }
            int gc = (tl & 7) * 128 + (tl >> 3) * 8 + hi * 2;
            union { unsigned u; float f; } c0, c1;
            c0.u = (unsigned)u0; c1.u = (unsigned)u1;
            hs[gc + (gc >> 5)] = c0.f;
            int g1 = gc + 1; hs[g1 + (g1 >> 5)] = c1.f;
        }
        __syncthreads();                       // #5: hs ready AND all 128 lines
                                               // verified >= st+1 block-wide
        // zero the buffer all Y(st) consumed: safe after #5 (every block has
        // passed its Y(st) reads, proven by the 128 epochs). 32 doubles per
        // block cover the 4096-double buffer exactly once.
        if (t < 32)
            gstored(scored + (size_t)((st + 1) & 1) * 4096 + (size_t)b * 32 + t, 0.0);
        {
            // att_v: wave tr computes col g_col+tr (16 fma/lane from hs)
            float acc = 0.f;
#pragma unroll
            for (int i = 0; i < 16; i++) {
                int k = i * 64 + li;
                acc = fmaf(watreg[i], hs[k + (k >> 5)], acc);
            }
            acc = wave_red(acc);
            if ((t & 63) == 0) attr[t >> 6] = acc;
            __syncthreads();                   // #6 (implicit vmcnt(0): zeroes)
            float ps = 0.f;
#pragma unroll
            for (int c = 0; c < 8; c++)
                ps = fmaf(wa8[c], fast_tanh(hpr[c] + attr[c]), ps);
            __asm__ volatile("" ::: "memory");
            __builtin_amdgcn_s_waitcnt(0);     // own zero-store drained first
            gatomicd(scored + (size_t)(st & 1) * 4096 + x * 512 + t,
                     (double)ps + BIAS32);
        }
        // s1 overlap for next step's gates (runs under the exchange latency)
        {
            float a = 0.f;
#pragma unroll
            for (int i = 0; i < 64; i++) {
                int k = kq * 64 + i;
                a = fmaf(hs[k + (k >> 5)], wregf[i], a);
            }
            red[kq * 32 + jt] = a;
        }
    }

    // ---- Epilogue: out[T-1] (Y(T) without gates) ----
    {
        const double* sp = scored + (size_t)((T_STEPS + 1) & 1) * 4096 + t;
        double vv[8];
        for (;;) {
            bool ok = true;
#pragma unroll
            for (int c = 0; c < 8; c++) {
                vv[c] = gloadd(sp + c * 512);
                ok = ok && (vv[c] > DONE_TH);
            }
            if (ok) break;
            __builtin_amdgcn_s_sleep(1);
        }
        double accd = 0.0;
#pragma unroll
        for (int c = 0; c < 8; c++) accd += (vv[c] - SUBBIAS);
        float evv = __expf((float)accd);
        le[t] = evv;
        float sv = wave_red(evv);
        if ((t & 63) == 0) sred[t >> 6] = sv;
        __syncthreads();
        float pp = 0.f;
#pragma unroll
        for (int i = 0; i < 8; i++)
            pp = fmaf(le[li + 64 * i], htr[i], pp);
        pp = wave_red(pp);
        if ((t & 63) == 0) sred2[t >> 6] = pp;
        __syncthreads();
        if (t < 8) {
            int g = g_col + t;
            float S = sum8(sred);
            float P = sred2[t];
            out[(size_t)(T_STEPS - 1) * 1024 + g] =
                hcolg + hs[g + (g >> 5)] - P / S;   // hs = h(T-1) from X(T-1)
        }
    }
}

extern "C" void kernel_launch(void* const* d_in, const int* in_sizes, int n_in,
                              void* d_out, int out_size, void* d_ws, size_t ws_size,
                              hipStream_t stream) {
    const float* inputs  = (const float*)d_in[0];
    const float* hiddn   = (const float*)d_in[1];
    const float* W_ioux  = (const float*)d_in[2];
    const float* b_ioux  = (const float*)d_in[3];
    const float* W_iouh  = (const float*)d_in[4];
    const float* b_iouh  = (const float*)d_in[5];
    const float* W_fx    = (const float*)d_in[6];
    const float* b_fx    = (const float*)d_in[7];
    const float* W_fh    = (const float*)d_in[8];
    const float* b_fh    = (const float*)d_in[9];
    const float* Wa      = (const float*)d_in[10];
    const float* W_attnh = (const float*)d_in[11];
    const float* b_attnh = (const float*)d_in[12];

    float* ws = (float*)d_ws;
    unsigned short* Wgb = (unsigned short*)(ws + OFF_WGB);
    float* WatT  = ws + OFF_WATT;
    float* HpreT = ws + OFF_HPRET;
    float* X_iou = ws + OFF_XIOU;
    float* X_f   = ws + OFF_XF;
    unsigned short* Gb = (unsigned short*)(ws + OFF_G);
    float* HT    = ws + OFF_HT;
    float* Hcol  = ws + OFF_HCOL;
    double* scored = (double*)(ws + OFF_SCORED);
    unsigned long long* hline = (unsigned long long*)(ws + OFF_HLINE);
    float* out   = (float*)d_out;

    // one memset covers Hcol (atomic target) .. scored .. hline (24576 floats)
    hipMemsetAsync(ws + OFF_HCOL, 0,
                   (OFF_HLINE + 2048 - OFF_HCOL) * sizeof(float), stream);

    prep<<<5664, 256, 0, stream>>>(W_iouh, W_fh, Wgb, W_attnh, WatT, hiddn, HT, Hcol);
    gemm_xh<<<896, 256, 0, stream>>>(inputs, W_ioux, W_fx, b_ioux, b_iouh, b_fx,
                                     b_fh, X_iou, X_f, hiddn, Wgb,
                                     W_attnh + 1024 * 1024, b_attnh, Gb, HpreT);

    recurrent<<<GRID, NTHR, 0, stream>>>(Wgb, WatT, HpreT, HT, Hcol, Gb,
                                         X_iou, X_f, Wa, hline, scored, out);
}